// Round 2
// baseline (434.168 us; speedup 1.0000x reference)
//
#include <hip/hip_runtime.h>
#include <hip/hip_bf16.h>

typedef __attribute__((ext_vector_type(4))) float f32x4;
typedef __attribute__((ext_vector_type(8))) short bf16x8;
typedef __attribute__((ext_vector_type(4))) short s16x4;

#define C_IN   64
#define HW_IN  64
#define D_OUT  512
#define K_TOT  4096

// A-window per K-step (one channel): 36 rows x 68 cols (zero-padded borders)
#define AROWS 36
#define ACOLS 68

__device__ __forceinline__ short f2bf(float x) {
    __hip_bfloat16 h = __float2bfloat16(x);
    return __builtin_bit_cast(short, h);
}

// ---------------- kernel 0: W f32 -> bf16 (N x K row-major) ----------------
__global__ void wcvt_kernel(const float* __restrict__ W, ushort* __restrict__ Wb) {
    int i = (blockIdx.x * 256 + threadIdx.x) * 4;
    if (i < D_OUT * K_TOT) {
        f32x4 v = *(const f32x4*)(W + i);
        s16x4 o;
        o[0] = f2bf(v[0]); o[1] = f2bf(v[1]); o[2] = f2bf(v[2]); o[3] = f2bf(v[3]);
        *(s16x4*)(Wb + i) = o;
    }
}

// ---------------- kernel 1: implicit-GEMM conv + bias + pos-enc ----------------
// Grid: 512 blocks = 128 M-tiles (x BM=128 tokens) x 4 N-tiles (x BN=128 of D).
// Block: 256 threads = 4 waves in a 2x2 grid, each wave owns a 64x64 sub-tile.
__global__ __launch_bounds__(256) void tok_gemm(
    const float* __restrict__ fm,     // (64, 64, 64, 64) f32
    const ushort* __restrict__ Wb,    // (512, 4096) bf16
    const float* __restrict__ bias,   // (512)
    float* __restrict__ out)          // (64, 256, 512) f32
{
    __shared__ __align__(16) float  Af[AROWS * ACOLS];   // raw f32 channel window
    __shared__ __align__(16) ushort Bu[128 * 72];        // bf16 W tile, pad 72

    const int bid   = blockIdx.x;
    const int mtile = bid & 127;     // consecutive bids share the W N-slice
    const int ntile = bid >> 7;

    const int bb   = mtile >> 1;     // batch image
    const int half = mtile & 1;      // top/bottom 8 rows of the 16x16 token grid
    const int row0 = half * 32 - 2;  // first input row of the window (oy0*4-2)

    const float* fmb = fm + (size_t)bb * (C_IN * HW_IN * HW_IN);

    const int tid  = threadIdx.x;
    const int lane = tid & 63;
    const int wid  = tid >> 6;
    const int wr   = wid >> 1;       // wave row (M)
    const int wc   = wid & 1;        // wave col (N)
    const int l15  = lane & 15;
    const int l4   = lane >> 4;

    f32x4 acc[4][4];
    #pragma unroll
    for (int mi = 0; mi < 4; ++mi)
        #pragma unroll
        for (int ni = 0; ni < 4; ++ni)
            acc[mi][ni] = (f32x4){0.f, 0.f, 0.f, 0.f};

    for (int c = 0; c < C_IN; ++c) {
        // ---- stage A: raw fm channel window (zero-padded) as f32
        const float* fmc = fmb + c * (HW_IN * HW_IN);
        for (int idx = tid; idx < AROWS * ACOLS; idx += 256) {
            int r   = idx / ACOLS;
            int col = idx - r * ACOLS;
            int rg  = row0 + r;
            int cg  = col - 2;
            float v = 0.0f;
            if ((unsigned)rg < 64u && (unsigned)cg < 64u)
                v = fmc[rg * 64 + cg];
            Af[idx] = v;
        }
        // ---- stage B: 128 rows x 64 bf16 of W for this channel, pad-72 rows
        const ushort* wsrc = Wb + (size_t)ntile * 128 * K_TOT + c * 64;
        #pragma unroll
        for (int it = 0; it < 4; ++it) {
            int u   = it * 256 + tid;     // 16B unit index, 1024 total
            int n   = u >> 3;
            int off = (u & 7) * 8;
            bf16x8 w = *(const bf16x8*)(wsrc + (size_t)n * K_TOT + off);
            *(bf16x8*)(Bu + n * 72 + off) = w;
        }
        __syncthreads();

        // ---- compute: 2 x (4 A-frags + 4 B-frags -> 16 MFMA)
        #pragma unroll
        for (int kk = 0; kk < 2; ++kk) {
            bf16x8 a[4], b[4];
            #pragma unroll
            for (int mi = 0; mi < 4; ++mi) {
                // ky = kk*4 + l4, token row-in-tile = wr*4+mi (per 16 tokens)
                int r = (wr * 4 + mi) * 4 + kk * 4 + l4;
                const float* ap = Af + r * ACOLS + l15 * 4;   // 8 contiguous kx
                f32x4 lo = *(const f32x4*)ap;
                f32x4 hi = *(const f32x4*)(ap + 4);
                bf16x8 t;
                t[0] = f2bf(lo[0]); t[1] = f2bf(lo[1]);
                t[2] = f2bf(lo[2]); t[3] = f2bf(lo[3]);
                t[4] = f2bf(hi[0]); t[5] = f2bf(hi[1]);
                t[6] = f2bf(hi[2]); t[7] = f2bf(hi[3]);
                a[mi] = t;
            }
            #pragma unroll
            for (int ni = 0; ni < 4; ++ni) {
                int n = wc * 64 + ni * 16 + l15;
                b[ni] = *(const bf16x8*)(Bu + n * 72 + kk * 32 + l4 * 8);
            }
            #pragma unroll
            for (int mi = 0; mi < 4; ++mi)
                #pragma unroll
                for (int ni = 0; ni < 4; ++ni)
                    acc[mi][ni] = __builtin_amdgcn_mfma_f32_16x16x32_bf16(
                        a[mi], b[ni], acc[mi][ni], 0, 0, 0);
        }
        __syncthreads();
    }

    // ---- epilogue: + bias + pos_encoding, write f32
    const float L2_1E4_DIV128 = 0.10381025296523007f;  // log2(10000)/128
    const int mbase = mtile * 128 + wr * 64;           // global M row base
    const int tb    = half * 128 + wr * 64;            // token base in image
    #pragma unroll
    for (int ni = 0; ni < 4; ++ni) {
        const int d    = ntile * 128 + wc * 64 + ni * 16 + l15;
        const float bv = bias[d];
        const int dd   = d & 255;
        const int fi   = dd & 127;
        const float invf  = exp2f(-L2_1E4_DIV128 * (float)fi);
        const bool use_sin = (dd < 128);   // wave-uniform
        const bool use_x   = (d < 256);    // block-uniform
        #pragma unroll
        for (int mi = 0; mi < 4; ++mi) {
            #pragma unroll
            for (int j = 0; j < 4; ++j) {
                int tm = mi * 16 + l4 * 4 + j;   // row within wave's 64
                int t  = tb + tm;                // token index in image
                int p  = use_x ? (t & 15) : (t >> 4);
                float arg = (float)p * invf;
                float pe  = use_sin ? __sinf(arg) : __cosf(arg);
                out[(size_t)(mbase + tm) * D_OUT + d] = acc[mi][ni][j] + bv + pe;
            }
        }
    }
}

extern "C" void kernel_launch(void* const* d_in, const int* in_sizes, int n_in,
                              void* d_out, int out_size, void* d_ws, size_t ws_size,
                              hipStream_t stream) {
    const float* fm   = (const float*)d_in[0];
    const float* W    = (const float*)d_in[1];
    const float* bias = (const float*)d_in[2];
    float* out = (float*)d_out;
    ushort* Wb = (ushort*)d_ws;   // 512*4096*2 = 4 MB

    wcvt_kernel<<<(D_OUT * K_TOT / 4 + 255) / 256, 256, 0, stream>>>(W, Wb);
    tok_gemm<<<512, 256, 0, stream>>>(fm, Wb, bias, out);
}

// Round 3
// 175.761 us; speedup vs baseline: 2.4702x; 2.4702x over previous
//
#include <hip/hip_runtime.h>
#include <hip/hip_bf16.h>

typedef __attribute__((ext_vector_type(4))) float f32x4;
typedef __attribute__((ext_vector_type(8))) short bf16x8;
typedef __attribute__((ext_vector_type(4))) short s16x4;

#define C_IN   64
#define HW_IN  64
#define D_OUT  512
#define K_TOT  4096

// A window: 36 rows x 72 (stride) bf16; valid interior cols 2..65, rest zero.
#define AROWS 36
#define ASTR  72
#define BSTR  72

__device__ __forceinline__ short f2bf(float x) {
    __hip_bfloat16 h = __float2bfloat16(x);
    return __builtin_bit_cast(short, h);
}
__device__ __forceinline__ uint pk2(float a, float b) {
    return (uint)(ushort)f2bf(a) | ((uint)(ushort)f2bf(b) << 16);
}

// ---------------- kernel 0: W f32 -> bf16 (N x K row-major) ----------------
__global__ void wcvt_kernel(const float* __restrict__ W, ushort* __restrict__ Wb) {
    int i = (blockIdx.x * 256 + threadIdx.x) * 4;
    if (i < D_OUT * K_TOT) {
        f32x4 v = *(const f32x4*)(W + i);
        s16x4 o;
        o[0] = f2bf(v[0]); o[1] = f2bf(v[1]); o[2] = f2bf(v[2]); o[3] = f2bf(v[3]);
        *(s16x4*)(Wb + i) = o;
    }
}

// ---------------- kernel 1: implicit-GEMM conv + bias + pos-enc ----------------
// Grid: 512 = 128 M-tiles (BM=128 tokens) x 4 N-tiles (BN=128 of D).
// Block: 256 threads = 4 waves (2x2), each wave a 64x64 sub-tile.
// Double-buffered, one barrier per channel; stage-issue before compute (T14).
__global__ __launch_bounds__(256) void tok_gemm(
    const float* __restrict__ fm,     // (64, 64, 64, 64) f32
    const ushort* __restrict__ Wb,    // (512, 4096) bf16
    const float* __restrict__ bias,   // (512)
    float* __restrict__ out)          // (64, 256, 512) f32
{
    __shared__ __align__(16) ushort As[2][AROWS * ASTR];   // bf16 channel window
    __shared__ __align__(16) ushort Bs[2][128 * BSTR];     // bf16 W tile

    const int bid   = blockIdx.x;
    const int mtile = bid & 127;
    const int ntile = bid >> 7;

    const int bb   = mtile >> 1;     // batch image
    const int half = mtile & 1;      // top/bottom 8 token rows

    const int tid  = threadIdx.x;
    const int lane = tid & 63;
    const int wid  = tid >> 6;
    const int wr   = wid >> 1;
    const int wc   = wid & 1;
    const int l15  = lane & 15;
    const int l4   = lane >> 4;

    // ---- zero-init A buffers once (pad cols + invalid rows stay 0 forever)
    for (int i = tid; i < 2 * AROWS * ASTR / 4; i += 256)
        ((unsigned long long*)As)[i] = 0ULL;

    const float* fmb = fm + (size_t)bb * (C_IN * HW_IN * HW_IN);
    const int rv0 = half ? 0 : 2;    // first valid window row
    const int rg0 = half ? 30 : 0;   // its global image row

    // per-thread A staging coords: u = it*256+tid (u<544), i=u>>4 (row 0..33), q=u&15
    const int i0 = tid >> 4,        q0 = tid & 15;
    const int i1 = (256 + tid) >> 4, q1 = tid & 15;         // (256+tid)&15 == tid&15
    const int i2 = (512 + tid) >> 4, q2 = tid & 15;
    const bool v2 = (tid < 32);                             // 512+tid < 544

    const ushort* wsrc = Wb + (size_t)(ntile * 128) * K_TOT;
    const int bn0 = (0 * 256 + tid) >> 3, bo0 = ((0 * 256 + tid) & 7) * 8;
    const int bn1 = (1 * 256 + tid) >> 3, bo1 = ((1 * 256 + tid) & 7) * 8;
    const int bn2 = (2 * 256 + tid) >> 3, bo2 = ((2 * 256 + tid) & 7) * 8;
    const int bn3 = (3 * 256 + tid) >> 3, bo3 = ((3 * 256 + tid) & 7) * 8;

    f32x4 acc[4][4];
    #pragma unroll
    for (int mi = 0; mi < 4; ++mi)
        #pragma unroll
        for (int ni = 0; ni < 4; ++ni)
            acc[mi][ni] = (f32x4){0.f, 0.f, 0.f, 0.f};

    f32x4 x0, x1, x2;
    bf16x8 w0, w1, w2, w3;

    // ---- issue + commit stage for a channel
    auto loadAB = [&](int c) {
        const float* fmc = fmb + c * (HW_IN * HW_IN);
        x0 = *(const f32x4*)(fmc + (rg0 + i0) * 64 + q0 * 4);
        x1 = *(const f32x4*)(fmc + (rg0 + i1) * 64 + q1 * 4);
        if (v2) x2 = *(const f32x4*)(fmc + (rg0 + i2) * 64 + q2 * 4);
        const ushort* ws = wsrc + c * 64;
        w0 = *(const bf16x8*)(ws + (size_t)bn0 * K_TOT + bo0);
        w1 = *(const bf16x8*)(ws + (size_t)bn1 * K_TOT + bo1);
        w2 = *(const bf16x8*)(ws + (size_t)bn2 * K_TOT + bo2);
        w3 = *(const bf16x8*)(ws + (size_t)bn3 * K_TOT + bo3);
    };
    auto storeAB = [&](int buf) {
        uint* A32 = (uint*)As[buf];
        // interior col' = 2+4q -> uint index 36*r + 1 + 2q (4B-aligned b32 writes)
        int d0 = 36 * (rv0 + i0) + 1 + 2 * q0;
        A32[d0] = pk2(x0[0], x0[1]); A32[d0 + 1] = pk2(x0[2], x0[3]);
        int d1 = 36 * (rv0 + i1) + 1 + 2 * q1;
        A32[d1] = pk2(x1[0], x1[1]); A32[d1 + 1] = pk2(x1[2], x1[3]);
        if (v2) {
            int d2 = 36 * (rv0 + i2) + 1 + 2 * q2;
            A32[d2] = pk2(x2[0], x2[1]); A32[d2 + 1] = pk2(x2[2], x2[3]);
        }
        ushort* B = Bs[buf];
        *(bf16x8*)(B + bn0 * BSTR + bo0) = w0;
        *(bf16x8*)(B + bn1 * BSTR + bo1) = w1;
        *(bf16x8*)(B + bn2 * BSTR + bo2) = w2;
        *(bf16x8*)(B + bn3 * BSTR + bo3) = w3;
    };
    auto compute = [&](int buf) {
        const ushort* A = As[buf];
        const ushort* B = Bs[buf];
        #pragma unroll
        for (int kk = 0; kk < 2; ++kk) {
            bf16x8 a[4], b[4];
            #pragma unroll
            for (int mi = 0; mi < 4; ++mi) {
                int r = (wr * 4 + mi) * 4 + kk * 4 + l4;   // window row = ty*4 + ky
                const ushort* ap = A + r * ASTR + l15 * 4; // 8 bf16, 8B-aligned
                s16x4 lo = *(const s16x4*)ap;
                s16x4 hi = *(const s16x4*)(ap + 4);
                a[mi] = (bf16x8){lo[0], lo[1], lo[2], lo[3], hi[0], hi[1], hi[2], hi[3]};
            }
            #pragma unroll
            for (int ni = 0; ni < 4; ++ni) {
                int n = wc * 64 + ni * 16 + l15;
                b[ni] = *(const bf16x8*)(B + n * BSTR + kk * 32 + l4 * 8);
            }
            #pragma unroll
            for (int mi = 0; mi < 4; ++mi)
                #pragma unroll
                for (int ni = 0; ni < 4; ++ni)
                    acc[mi][ni] = __builtin_amdgcn_mfma_f32_16x16x32_bf16(
                        a[mi], b[ni], acc[mi][ni], 0, 0, 0);
        }
    };

    // ---- prologue: zero-init visible, then stage c=0
    __syncthreads();
    loadAB(0);
    storeAB(0);
    __syncthreads();

    // ---- main loop: one barrier per channel, loads overlap compute
    for (int c = 0; c < 64; ++c) {
        const int cur = c & 1;
        if (c < 63) loadAB(c + 1);          // issue early (latency under compute)
        compute(cur);
        if (c < 63) storeAB(cur ^ 1);       // commit late (writes other buffer)
        __syncthreads();
    }

    // ---- epilogue: + bias + pos_encoding
    const float L2_1E4_DIV128 = 0.10381025296523007f;  // log2(10000)/128
    const int mbase = mtile * 128 + wr * 64;
    const int tb    = half * 128 + wr * 64;
    #pragma unroll
    for (int ni = 0; ni < 4; ++ni) {
        const int d    = ntile * 128 + wc * 64 + ni * 16 + l15;
        const float bv = bias[d];
        const int dd   = d & 255;
        const int fi   = dd & 127;
        const float invf   = exp2f(-L2_1E4_DIV128 * (float)fi);
        const bool use_sin = (dd < 128);
        const bool use_x   = (d < 256);
        #pragma unroll
        for (int mi = 0; mi < 4; ++mi) {
            #pragma unroll
            for (int j = 0; j < 4; ++j) {
                int tm = mi * 16 + l4 * 4 + j;
                int t  = tb + tm;
                int p  = use_x ? (t & 15) : (t >> 4);
                float arg = (float)p * invf;
                float pe  = use_sin ? __sinf(arg) : __cosf(arg);
                out[(size_t)(mbase + tm) * D_OUT + d] = acc[mi][ni][j] + bv + pe;
            }
        }
    }
}

extern "C" void kernel_launch(void* const* d_in, const int* in_sizes, int n_in,
                              void* d_out, int out_size, void* d_ws, size_t ws_size,
                              hipStream_t stream) {
    const float* fm   = (const float*)d_in[0];
    const float* W    = (const float*)d_in[1];
    const float* bias = (const float*)d_in[2];
    float* out = (float*)d_out;
    ushort* Wb = (ushort*)d_ws;   // 512*4096*2 = 4 MB

    wcvt_kernel<<<(D_OUT * K_TOT / 4 + 255) / 256, 256, 0, stream>>>(W, Wb);
    tok_gemm<<<512, 256, 0, stream>>>(fm, Wb, bias, out);
}

// Round 4
// 164.436 us; speedup vs baseline: 2.6404x; 1.0689x over previous
//
#include <hip/hip_runtime.h>
#include <hip/hip_bf16.h>

typedef __attribute__((ext_vector_type(4))) float f32x4;
typedef __attribute__((ext_vector_type(8))) short bf16x8;
typedef __attribute__((ext_vector_type(4))) short s16x4;

#define C_IN   64
#define HW_IN  64
#define D_OUT  512
#define K_TOT  4096

// A window: 36 rows x 72 (stride) bf16; valid interior cols 2..65, rest zero.
#define AROWS 36
#define ASTR  72
#define BSTR  72

__device__ __forceinline__ short f2bf(float x) {
    __hip_bfloat16 h = __float2bfloat16(x);
    return __builtin_bit_cast(short, h);
}
__device__ __forceinline__ uint pk2(float a, float b) {
    return (uint)(ushort)f2bf(a) | ((uint)(ushort)f2bf(b) << 16);
}

// ---------------- kernel 0: W f32 -> bf16 (N x K row-major) ----------------
__global__ void wcvt_kernel(const float* __restrict__ W, ushort* __restrict__ Wb) {
    int i = (blockIdx.x * 256 + threadIdx.x) * 4;
    if (i < D_OUT * K_TOT) {
        f32x4 v = *(const f32x4*)(W + i);
        s16x4 o;
        o[0] = f2bf(v[0]); o[1] = f2bf(v[1]); o[2] = f2bf(v[2]); o[3] = f2bf(v[3]);
        *(s16x4*)(Wb + i) = o;
    }
}

// ---------------- kernel 1: implicit-GEMM conv + bias + pos-enc ----------------
// Grid: 512 = 128 M-tiles (BM=128 tokens) x 4 N-tiles (BN=128 of D).
// Block: 256 threads = 4 waves (2x2), each wave a 64x64 sub-tile.
// Double-buffered LDS + DEPTH-2 register prefetch (named sets, stride-2 loop).
__global__ __launch_bounds__(256) void tok_gemm(
    const float* __restrict__ fm,     // (64, 64, 64, 64) f32
    const ushort* __restrict__ Wb,    // (512, 4096) bf16
    const float* __restrict__ bias,   // (512)
    float* __restrict__ out)          // (64, 256, 512) f32
{
    __shared__ __align__(16) ushort As[2][AROWS * ASTR];   // bf16 channel window
    __shared__ __align__(16) ushort Bs[2][128 * BSTR];     // bf16 W tile

    const int bid   = blockIdx.x;
    const int mtile = bid & 127;
    const int ntile = bid >> 7;

    const int bb   = mtile >> 1;     // batch image
    const int half = mtile & 1;      // top/bottom 8 token rows

    const int tid  = threadIdx.x;
    const int lane = tid & 63;
    const int wid  = tid >> 6;
    const int wr   = wid >> 1;
    const int wc   = wid & 1;
    const int l15  = lane & 15;
    const int l4   = lane >> 4;

    // ---- zero-init A buffers once (pad cols + invalid rows stay 0 forever)
    for (int i = tid; i < 2 * AROWS * ASTR / 4; i += 256)
        ((unsigned long long*)As)[i] = 0ULL;

    const float* fmb = fm + (size_t)bb * (C_IN * HW_IN * HW_IN);
    const int rv0 = half ? 0 : 2;    // first valid window row
    const int rg0 = half ? 30 : 0;   // its global image row

    // per-thread A staging coords: u = it*256+tid (u<544), i=u>>4 (row 0..33), q=u&15
    const int i0 = tid >> 4;
    const int i1 = 16 + i0;
    const int i2 = 32 + i0;
    const int q0 = tid & 15;
    const bool v2 = (tid < 32);      // 512+tid < 544

    const ushort* wsrc = Wb + (size_t)(ntile * 128) * K_TOT;
    const int bn0 = tid >> 3,        bo0 = (tid & 7) * 8;
    const int bn1 = 32 + (tid >> 3);
    const int bn2 = 64 + (tid >> 3);
    const int bn3 = 96 + (tid >> 3);

    f32x4 acc[4][4];
    #pragma unroll
    for (int mi = 0; mi < 4; ++mi)
        #pragma unroll
        for (int ni = 0; ni < 4; ++ni)
            acc[mi][ni] = (f32x4){0.f, 0.f, 0.f, 0.f};

    struct Set { f32x4 x0, x1, x2; bf16x8 w0, w1, w2, w3; };
    Set SA, SB;

    auto loadAB = [&](int c, Set& s) {
        const float* fmc = fmb + c * (HW_IN * HW_IN);
        s.x0 = *(const f32x4*)(fmc + (rg0 + i0) * 64 + q0 * 4);
        s.x1 = *(const f32x4*)(fmc + (rg0 + i1) * 64 + q0 * 4);
        if (v2) s.x2 = *(const f32x4*)(fmc + (rg0 + i2) * 64 + q0 * 4);
        const ushort* ws = wsrc + c * 64;
        s.w0 = *(const bf16x8*)(ws + (size_t)bn0 * K_TOT + bo0);
        s.w1 = *(const bf16x8*)(ws + (size_t)bn1 * K_TOT + bo0);
        s.w2 = *(const bf16x8*)(ws + (size_t)bn2 * K_TOT + bo0);
        s.w3 = *(const bf16x8*)(ws + (size_t)bn3 * K_TOT + bo0);
    };
    auto storeAB = [&](const Set& s, int buf) {
        uint* A32 = (uint*)As[buf];
        // interior col' = 2+4q -> uint index 36*r + 1 + 2q (4B-aligned b32 writes)
        int d0 = 36 * (rv0 + i0) + 1 + 2 * q0;
        A32[d0] = pk2(s.x0[0], s.x0[1]); A32[d0 + 1] = pk2(s.x0[2], s.x0[3]);
        int d1 = 36 * (rv0 + i1) + 1 + 2 * q0;
        A32[d1] = pk2(s.x1[0], s.x1[1]); A32[d1 + 1] = pk2(s.x1[2], s.x1[3]);
        if (v2) {
            int d2 = 36 * (rv0 + i2) + 1 + 2 * q0;
            A32[d2] = pk2(s.x2[0], s.x2[1]); A32[d2 + 1] = pk2(s.x2[2], s.x2[3]);
        }
        ushort* B = Bs[buf];
        *(bf16x8*)(B + bn0 * BSTR + bo0) = s.w0;
        *(bf16x8*)(B + bn1 * BSTR + bo0) = s.w1;
        *(bf16x8*)(B + bn2 * BSTR + bo0) = s.w2;
        *(bf16x8*)(B + bn3 * BSTR + bo0) = s.w3;
    };
    auto compute = [&](int buf) {
        const ushort* A = As[buf];
        const ushort* B = Bs[buf];
        #pragma unroll
        for (int kk = 0; kk < 2; ++kk) {
            bf16x8 a[4], b[4];
            #pragma unroll
            for (int mi = 0; mi < 4; ++mi) {
                int r = (wr * 4 + mi) * 4 + kk * 4 + l4;   // window row = ty*4 + ky
                const ushort* ap = A + r * ASTR + l15 * 4; // 8 contiguous bf16
                s16x4 lo = *(const s16x4*)ap;
                s16x4 hi = *(const s16x4*)(ap + 4);
                a[mi] = (bf16x8){lo[0], lo[1], lo[2], lo[3], hi[0], hi[1], hi[2], hi[3]};
            }
            #pragma unroll
            for (int ni = 0; ni < 4; ++ni) {
                int n = wc * 64 + ni * 16 + l15;
                b[ni] = *(const bf16x8*)(B + n * BSTR + kk * 32 + l4 * 8);
            }
            #pragma unroll
            for (int mi = 0; mi < 4; ++mi)
                #pragma unroll
                for (int ni = 0; ni < 4; ++ni)
                    acc[mi][ni] = __builtin_amdgcn_mfma_f32_16x16x32_bf16(
                        a[mi], b[ni], acc[mi][ni], 0, 0, 0);
        }
    };

    // ---- prologue: zero-init visible, then stage ch0/ch1 (depth-2 in flight)
    __syncthreads();
    loadAB(0, SA);
    loadAB(1, SB);
    storeAB(SA, 0);          // waits only SA's loads; SB stays in flight
    __syncthreads();

    // ---- main loop, stride 2: loads issued 2 channels ahead of their store
    for (int c = 0; c < 64; c += 2) {
        if (c + 2 < 64) loadAB(c + 2, SA);   // SA free (ch c already in LDS)
        compute(0);                           // ch c
        storeAB(SB, 1);                       // ch c+1 (loads ~1 iter old)
        __syncthreads();

        if (c + 3 < 64) loadAB(c + 3, SB);
        compute(1);                           // ch c+1
        if (c + 2 < 64) storeAB(SA, 0);       // ch c+2
        __syncthreads();
    }

    // ---- epilogue: + bias + pos_encoding
    const float L2_1E4_DIV128 = 0.10381025296523007f;  // log2(10000)/128
    const int mbase = mtile * 128 + wr * 64;
    const int tb    = half * 128 + wr * 64;
    #pragma unroll
    for (int ni = 0; ni < 4; ++ni) {
        const int d    = ntile * 128 + wc * 64 + ni * 16 + l15;
        const float bv = bias[d];
        const int dd   = d & 255;
        const int fi   = dd & 127;
        const float invf   = exp2f(-L2_1E4_DIV128 * (float)fi);
        const bool use_sin = (dd < 128);
        const bool use_x   = (d < 256);
        #pragma unroll
        for (int mi = 0; mi < 4; ++mi) {
            #pragma unroll
            for (int j = 0; j < 4; ++j) {
                int tm = mi * 16 + l4 * 4 + j;
                int t  = tb + tm;
                int p  = use_x ? (t & 15) : (t >> 4);
                float arg = (float)p * invf;
                float pe  = use_sin ? __sinf(arg) : __cosf(arg);
                out[(size_t)(mbase + tm) * D_OUT + d] = acc[mi][ni][j] + bv + pe;
            }
        }
    }
}

extern "C" void kernel_launch(void* const* d_in, const int* in_sizes, int n_in,
                              void* d_out, int out_size, void* d_ws, size_t ws_size,
                              hipStream_t stream) {
    const float* fm   = (const float*)d_in[0];
    const float* W    = (const float*)d_in[1];
    const float* bias = (const float*)d_in[2];
    float* out = (float*)d_out;
    ushort* Wb = (ushort*)d_ws;   // 512*4096*2 = 4 MB

    wcvt_kernel<<<(D_OUT * K_TOT / 4 + 255) / 256, 256, 0, stream>>>(W, Wb);
    tok_gemm<<<512, 256, 0, stream>>>(fm, Wb, bias, out);
}